// Round 5
// baseline (9083.696 us; speedup 1.0000x reference)
//
#include <hip/hip_runtime.h>
#include <math.h>

#define B 512
#define S 256
#define D 64
#define H 512
#define BH (B*H)

// workspace layout (floats) — identical footprint to round-2 (known to fit)
#define HBUF_OFF 0            // 2 slots of B*H fp32 h
#define CBUF_OFF (2*BH)       // 2 slots of B*H fp32 c
#define XATT_OFF (4*BH)       // B*D fp32 x_att

typedef __attribute__((ext_vector_type(8))) short short8;   // 8 x bf16 bits
typedef __attribute__((ext_vector_type(4))) float f32x4;

__device__ inline unsigned short f2bf(float v) {            // fp32 -> bf16 (RNE)
    unsigned int u = __float_as_uint(v);
    unsigned int r = (u + 0x7fffu + ((u >> 16) & 1u)) >> 16;
    return (unsigned short)r;
}
__device__ inline float bf2f(unsigned short b) {
    return __uint_as_float(((unsigned int)b) << 16);
}
__device__ inline float readlane_f(float v, int l) {
    return __uint_as_float(__builtin_amdgcn_readlane(__float_as_uint(v), l));
}

__global__ __launch_bounds__(256) void init_zero(float* __restrict__ ws) {
    int i = blockIdx.x * blockDim.x + threadIdx.x;
    if (i < BH) {
        ws[HBUF_OFF + i] = 0.f;
        ws[CBUF_OFF + i] = 0.f;
    }
}

// Attention gate. 128 WGs x 4 rows. 4 waves k-split the 1088-long dot, LDS
// stages [x|h|c] per row; row values broadcast via v_readlane (SGPR-operand FMA).
__global__ __launch_bounds__(256) void attn_kernel(
    const float* __restrict__ x, const float* __restrict__ Wa,
    const float* __restrict__ Ua, const float* __restrict__ ba,
    const float* __restrict__ Va, float* __restrict__ ws, int t)
{
    const int tid = threadIdx.x;
    const int lane = tid & 63;
    const int w = tid >> 6;
    const int b0 = blockIdx.x * 4;
    const int rd = t & 1;

    __shared__ float hcx[4][1092];    // [row][k]: 0..63 x, 64..575 h, 576..1087 c
    __shared__ float part[4][4][64];  // [wave][row][d]
    __shared__ float ta4[4][64];

    const float* __restrict__ hbuf = ws + HBUF_OFF + rd*BH;
    const float* __restrict__ cbuf = ws + CBUF_OFF + rd*BH;

    {   // stage: wave w stages row w (272 float4 = 1088 floats)
        const float4* xs = (const float4*)(x + ((size_t)(b0 + w)*S + t)*D);
        const float4* hs = (const float4*)(hbuf + (size_t)(b0 + w)*H);
        const float4* cs = (const float4*)(cbuf + (size_t)(b0 + w)*H);
        for (int c = lane; c < 272; c += 64) {
            float4 v;
            if (c < 16) v = xs[c];
            else if (c < 144) v = hs[c - 16];
            else v = cs[c - 144];
            *(float4*)&hcx[w][c*4] = v;
        }
    }
    __syncthreads();

    // phase 1: wave w covers k in [w*272, w*272+272)
    float acc0 = 0.f, acc1 = 0.f, acc2 = 0.f, acc3 = 0.f;
    const int k0 = w * 272;
    for (int kb = 0; kb < 272; kb += 64) {
        const int base = k0 + kb;
        int n = 272 - kb; if (n > 64) n = 64;
        int ii = base + lane; if (ii > 1087) ii = 1087;   // clamp (tail lanes unused)
        float hv0 = hcx[0][ii];
        float hv1 = hcx[1][ii];
        float hv2 = hcx[2][ii];
        float hv3 = hcx[3][ii];
        #pragma unroll 8
        for (int j = 0; j < n; ++j) {
            const int k = base + j;
            const float* wrow = (k < 64) ? (Wa + k*D) : (Ua + (size_t)(k - 64)*D);
            float uv = wrow[lane];
            acc0 += readlane_f(hv0, j) * uv;
            acc1 += readlane_f(hv1, j) * uv;
            acc2 += readlane_f(hv2, j) * uv;
            acc3 += readlane_f(hv3, j) * uv;
        }
    }
    part[w][0][lane] = acc0;
    part[w][1][lane] = acc1;
    part[w][2][lane] = acc2;
    part[w][3][lane] = acc3;
    __syncthreads();
    {   // reduce + tanh: wave w handles row w
        float pre = ba[lane] + part[0][w][lane] + part[1][w][lane]
                  + part[2][w][lane] + part[3][w][lane];
        ta4[w][lane] = tanhf(pre);
    }
    __syncthreads();
    {   // phase 2 + softmax + write x_att: wave w = row w
        float tv = ta4[w][lane];
        float v = 0.f;
        #pragma unroll 8
        for (int j = 0; j < 64; ++j)
            v += readlane_f(tv, j) * Va[j*D + lane];
        float m = v;
        #pragma unroll
        for (int o = 32; o > 0; o >>= 1) m = fmaxf(m, __shfl_xor(m, o));
        float e = expf(v - m);
        float ssum = e;
        #pragma unroll
        for (int o = 32; o > 0; o >>= 1) ssum += __shfl_xor(ssum, o);
        ws[XATT_OFF + (size_t)(b0 + w)*D + lane] = (e / ssum) * hcx[w][lane];
    }
}

// Gate GEMM via bf16-split 3-pass MFMA + fused LSTM state update.
// grid (32,8): ut = 16-unit tile (all 4 gates interleaved: j = u_loc*4 + q),
// rt = 64-row tile. 4 waves in 2x2, each 32x32 output via 2x2 mfma 16x16x32.
__global__ __launch_bounds__(256) void gates_kernel(
    const float* __restrict__ Wih, const float* __restrict__ Whh,
    const float* __restrict__ bih, const float* __restrict__ bhh,
    float* __restrict__ ws, int t)
{
    const int tid = threadIdx.x;
    const int lane = tid & 63;
    const int wid = tid >> 6;
    const int wr = wid >> 1, wc = wid & 1;
    const int ut = blockIdx.x;
    const int rt = blockIdx.y;
    const int b0 = rt * 64;
    const int u_base = ut * 16;

    __shared__ __align__(16) unsigned short aHi[64][72];  // act hi  (pad: 144B rows)
    __shared__ __align__(16) unsigned short aLo[64][72];
    __shared__ __align__(16) unsigned short bHi[64][72];  // weight hi
    __shared__ __align__(16) unsigned short bLo[64][72];
    __shared__ float gout[64][66];                        // epilogue transpose

    const int rd = t & 1, wrs = rd ^ 1;
    const float* __restrict__ hbuf_r = ws + HBUF_OFF + rd*BH;
    const float* __restrict__ cbuf_r = ws + CBUF_OFF + rd*BH;
    float* __restrict__ hbuf_w = ws + HBUF_OFF + wrs*BH;
    float* __restrict__ cbuf_w = ws + CBUF_OFF + wrs*BH;
    const float* __restrict__ xatt = ws + XATT_OFF;

    const int srow = tid >> 2;                       // staging row 0..63
    const int c4 = tid & 3;
    const int Wrow = (srow & 3)*H + u_base + (srow >> 2);  // q*H + u

    f32x4 acc00 = {0,0,0,0}, acc01 = {0,0,0,0}, acc10 = {0,0,0,0}, acc11 = {0,0,0,0};
    float4 aReg[4], bReg[4];

    auto loadChunk = [&](int kb) {
        const float* asrc; const float* bsrc;
        if (kb < 8) {
            asrc = hbuf_r + (size_t)(b0 + srow)*H + kb*64;
            bsrc = Whh + (size_t)Wrow*H + kb*64;
        } else {
            asrc = xatt + (size_t)(b0 + srow)*D;
            bsrc = Wih + (size_t)Wrow*D;
        }
        #pragma unroll
        for (int it = 0; it < 4; ++it) {
            const int f = c4 + 4*it;
            aReg[it] = *(const float4*)(asrc + f*4);
            bReg[it] = *(const float4*)(bsrc + f*4);
        }
    };
    auto storeChunk = [&]() {
        #pragma unroll
        for (int it = 0; it < 4; ++it) {
            const int f = c4 + 4*it;
            float4 av = aReg[it], bv = bReg[it];
            ushort4 ah, al, bh, bl;
            ah.x = f2bf(av.x); al.x = f2bf(av.x - bf2f(ah.x));
            ah.y = f2bf(av.y); al.y = f2bf(av.y - bf2f(ah.y));
            ah.z = f2bf(av.z); al.z = f2bf(av.z - bf2f(ah.z));
            ah.w = f2bf(av.w); al.w = f2bf(av.w - bf2f(ah.w));
            bh.x = f2bf(bv.x); bl.x = f2bf(bv.x - bf2f(bh.x));
            bh.y = f2bf(bv.y); bl.y = f2bf(bv.y - bf2f(bh.y));
            bh.z = f2bf(bv.z); bl.z = f2bf(bv.z - bf2f(bh.z));
            bh.w = f2bf(bv.w); bl.w = f2bf(bv.w - bf2f(bh.w));
            *(ushort4*)&aHi[srow][f*4] = ah;
            *(ushort4*)&aLo[srow][f*4] = al;
            *(ushort4*)&bHi[srow][f*4] = bh;
            *(ushort4*)&bLo[srow][f*4] = bl;
        }
    };

    loadChunk(0);
    for (int kb = 0; kb < 9; ++kb) {
        __syncthreads();                  // previous chunk's mfma done with LDS
        storeChunk();                     // (waits vmcnt on aReg/bReg here)
        __syncthreads();                  // tile visible
        if (kb < 8) loadChunk(kb + 1);    // prefetch hides L2 latency under mfma
        #pragma unroll
        for (int ks = 0; ks < 2; ++ks) {
            const int col = ks*32 + (lane >> 4)*8;
            const int ar0 = wr*32 + (lane & 15);
            const int br0 = wc*32 + (lane & 15);
            short8 ah0 = *(const short8*)&aHi[ar0][col];
            short8 ah1 = *(const short8*)&aHi[ar0 + 16][col];
            short8 al0 = *(const short8*)&aLo[ar0][col];
            short8 al1 = *(const short8*)&aLo[ar0 + 16][col];
            short8 bh0 = *(const short8*)&bHi[br0][col];
            short8 bh1 = *(const short8*)&bHi[br0 + 16][col];
            short8 bl0 = *(const short8*)&bLo[br0][col];
            short8 bl1 = *(const short8*)&bLo[br0 + 16][col];
            acc00 = __builtin_amdgcn_mfma_f32_16x16x32_bf16(ah0, bh0, acc00, 0,0,0);
            acc01 = __builtin_amdgcn_mfma_f32_16x16x32_bf16(ah0, bh1, acc01, 0,0,0);
            acc10 = __builtin_amdgcn_mfma_f32_16x16x32_bf16(ah1, bh0, acc10, 0,0,0);
            acc11 = __builtin_amdgcn_mfma_f32_16x16x32_bf16(ah1, bh1, acc11, 0,0,0);
            acc00 = __builtin_amdgcn_mfma_f32_16x16x32_bf16(ah0, bl0, acc00, 0,0,0);
            acc01 = __builtin_amdgcn_mfma_f32_16x16x32_bf16(ah0, bl1, acc01, 0,0,0);
            acc10 = __builtin_amdgcn_mfma_f32_16x16x32_bf16(ah1, bl0, acc10, 0,0,0);
            acc11 = __builtin_amdgcn_mfma_f32_16x16x32_bf16(ah1, bl1, acc11, 0,0,0);
            acc00 = __builtin_amdgcn_mfma_f32_16x16x32_bf16(al0, bh0, acc00, 0,0,0);
            acc01 = __builtin_amdgcn_mfma_f32_16x16x32_bf16(al0, bh1, acc01, 0,0,0);
            acc10 = __builtin_amdgcn_mfma_f32_16x16x32_bf16(al1, bh0, acc10, 0,0,0);
            acc11 = __builtin_amdgcn_mfma_f32_16x16x32_bf16(al1, bh1, acc11, 0,0,0);
        }
    }

    {   // D layout: row=(lane>>4)*4+r, col=lane&15 within each 16x16 tile
        const int m0 = (lane >> 4)*4;
        const int n0 = lane & 15;
        #pragma unroll
        for (int r = 0; r < 4; ++r) {
            gout[wr*32 + m0 + r     ][wc*32 + n0     ] = acc00[r];
            gout[wr*32 + m0 + r     ][wc*32 + 16 + n0] = acc01[r];
            gout[wr*32 + 16 + m0 + r][wc*32 + n0     ] = acc10[r];
            gout[wr*32 + 16 + m0 + r][wc*32 + 16 + n0] = acc11[r];
        }
    }
    __syncthreads();
    {   // fused state update: all 4 gates of unit u are cols u16*4 + {0,1,2,3}
        const int u16 = tid & 15;
        const int u_glob = u_base + u16;
        const float bs0 = bih[0*H + u_glob] + bhh[0*H + u_glob];
        const float bs1 = bih[1*H + u_glob] + bhh[1*H + u_glob];
        const float bs2 = bih[2*H + u_glob] + bhh[2*H + u_glob];
        const float bs3 = bih[3*H + u_glob] + bhh[3*H + u_glob];
        #pragma unroll
        for (int pass = 0; pass < 4; ++pass) {
            const int b_loc = (tid >> 4) + pass*16;
            const int b = b0 + b_loc;
            float2 g01 = *(const float2*)&gout[b_loc][u16*4];
            float2 g23 = *(const float2*)&gout[b_loc][u16*4 + 2];
            float gi = g01.x + bs0;
            float gf = g01.y + bs1;
            float gg = g23.x + bs2;
            float go = g23.y + bs3;
            float c_old = cbuf_r[(size_t)b*H + u_glob];
            float si = 1.f/(1.f + expf(-gi));
            float sf = 1.f/(1.f + expf(-gf));
            float so = 1.f/(1.f + expf(-go));
            float cn = sf*c_old + si*tanhf(gg);
            float hn = so*tanhf(cn);
            cbuf_w[(size_t)b*H + u_glob] = cn;
            hbuf_w[(size_t)b*H + u_glob] = hn;
        }
    }
}

__global__ __launch_bounds__(256) void fc_kernel(
    const float* __restrict__ fcw, const float* __restrict__ fcb,
    const float* __restrict__ ws, float* __restrict__ out)
{
    const int b = blockIdx.x;
    __shared__ float hrow[H];
    const float* __restrict__ hp = ws + HBUF_OFF + (size_t)b*H;  // final h in slot 0 (S even)
    for (int k = threadIdx.x; k < H; k += 256) hrow[k] = hp[k];
    __syncthreads();
    int j = threadIdx.x;
    if (j < 24) {
        float a = fcb[j];
        #pragma unroll 8
        for (int k = 0; k < H; ++k) a += hrow[k] * fcw[j*H + k];
        out[b*24 + j] = a;
    }
}

extern "C" void kernel_launch(void* const* d_in, const int* in_sizes, int n_in,
                              void* d_out, int out_size, void* d_ws, size_t ws_size,
                              hipStream_t stream) {
    const float* x   = (const float*)d_in[0];
    const float* Wa  = (const float*)d_in[1];
    const float* Ua  = (const float*)d_in[2];
    const float* ba  = (const float*)d_in[3];
    const float* Va  = (const float*)d_in[4];
    const float* Wih = (const float*)d_in[5];
    const float* Whh = (const float*)d_in[6];
    const float* bih = (const float*)d_in[7];
    const float* bhh = (const float*)d_in[8];
    const float* fcw = (const float*)d_in[9];
    const float* fcb = (const float*)d_in[10];
    float* out = (float*)d_out;
    float* ws  = (float*)d_ws;

    hipLaunchKernelGGL(init_zero, dim3((BH + 255)/256), dim3(256), 0, stream, ws);
    for (int t = 0; t < S; ++t) {
        hipLaunchKernelGGL(attn_kernel, dim3(B/4), dim3(256), 0, stream,
                           x, Wa, Ua, ba, Va, ws, t);
        hipLaunchKernelGGL(gates_kernel, dim3(32, 8), dim3(256), 0, stream,
                           Wih, Whh, bih, bhh, ws, t);
    }
    hipLaunchKernelGGL(fc_kernel, dim3(B), dim3(256), 0, stream, fcw, fcb, ws, out);
}

// Round 6
// 8383.716 us; speedup vs baseline: 1.0835x; 1.0835x over previous
//
#include <hip/hip_runtime.h>
#include <math.h>

#define B 512
#define S 256
#define D 64
#define H 512
#define BH (B*H)

// ---- workspace byte offsets ----
// h32  : 2 slots * BH fp32   @ 0         (2 MB)
// c32  : 1 slot  * BH fp32   @ 2*BH*4    (1 MB, updated in place)
// hHi  : 2 slots * BH u16    @ 3*BH*4    (1 MB)
// hLo  : 2 slots * BH u16    @ +2*BH*2   (1 MB)
// xHi  : B*D u16             @ +2*BH*2   (64 KB)
// xLo  : B*D u16             @ +B*D*2    (64 KB)
// wswz : 32*9*2*2*64*32 u16  @ +B*D*2    (4.5 MB)  [ut][kb][half][ks][row64][cg4*8]
// total ~9.63 MB

typedef __attribute__((ext_vector_type(8))) short short8;
typedef __attribute__((ext_vector_type(4))) float f32x4;

__device__ inline unsigned short f2bf(float v) {            // fp32 -> bf16 RNE
    unsigned int u = __float_as_uint(v);
    unsigned int r = (u + 0x7fffu + ((u >> 16) & 1u)) >> 16;
    return (unsigned short)r;
}
__device__ inline float bf2f(unsigned short b) {
    return __uint_as_float(((unsigned int)b) << 16);
}

__global__ __launch_bounds__(256) void init_zero(
    float* __restrict__ h32, float* __restrict__ c32,
    unsigned short* __restrict__ hHi, unsigned short* __restrict__ hLo)
{
    int i = blockIdx.x * blockDim.x + threadIdx.x;
    if (i < BH) {
        h32[i] = 0.f;      // slot 0
        c32[i] = 0.f;
        hHi[i] = 0;        // slot 0 (bf16 +0.0)
        hLo[i] = 0;
    }
}

// Pre-split Whh/Wih into swizzled bf16 hi/lo fragment layout. Runs once per launch.
// block (ut, kb); thread t: j'row = t>>2, 16 cols starting (t&3)*16.
__global__ __launch_bounds__(256) void prep_weights(
    const float* __restrict__ Whh, const float* __restrict__ Wih,
    unsigned short* __restrict__ wswz)
{
    const int ut = blockIdx.x;
    const int kb = blockIdx.y;
    const int t = threadIdx.x;
    const int srow = t >> 2;
    const int cc0 = (t & 3) * 16;
    const int Wrow = (srow & 3)*H + ut*16 + (srow >> 2);   // q*H + u

    const float* src = (kb < 8) ? (Whh + (size_t)Wrow*H + kb*64 + cc0)
                                : (Wih + (size_t)Wrow*D + cc0);
    float v[16];
    #pragma unroll
    for (int i = 0; i < 4; ++i)
        *(float4*)&v[i*4] = *(const float4*)(src + i*4);

    unsigned short hi[16], lo[16];
    #pragma unroll
    for (int e = 0; e < 16; ++e) {
        hi[e] = f2bf(v[e]);
        lo[e] = f2bf(v[e] - bf2f(hi[e]));
    }
    #pragma unroll
    for (int g = 0; g < 2; ++g) {
        const int cc = cc0 + g*8;
        const int ks = cc >> 5;
        const int cg = (cc >> 3) & 3;
        size_t bh = ((((size_t)(ut*9 + kb)*2 + 0)*2 + ks)*64 + srow)*32 + cg*8;
        size_t bl = ((((size_t)(ut*9 + kb)*2 + 1)*2 + ks)*64 + srow)*32 + cg*8;
        *(short8*)(wswz + bh) = *(const short8*)&hi[g*8];
        *(short8*)(wswz + bl) = *(const short8*)&lo[g*8];
    }
}

// Attention gate — round-2 structure (measured 4.8us). One WG per 2 rows.
__global__ __launch_bounds__(256) void attn_kernel(
    const float* __restrict__ x, const float* __restrict__ Wa,
    const float* __restrict__ Ua, const float* __restrict__ ba,
    const float* __restrict__ Va,
    const float* __restrict__ h32, const float* __restrict__ c32,
    unsigned short* __restrict__ xHi, unsigned short* __restrict__ xLo, int t)
{
    const int d = threadIdx.x & 63;
    const int r = (threadIdx.x >> 6) & 1;
    const int p = threadIdx.x >> 7;
    const int b = blockIdx.x * 2 + r;

    const int rd = t & 1;
    const float* __restrict__ hrow = h32 + (size_t)rd*BH + (size_t)b*H;
    const float* __restrict__ crow = c32 + (size_t)b*H;
    const float* __restrict__ xrow = x + ((size_t)b*S + t)*D;

    __shared__ float part[2][2][64];
    __shared__ float ta[2][64];
    __shared__ float pv[2][2][64];

    float a = 0.f;
    if (p == 0) {
        a = ba[d];
        #pragma unroll 8
        for (int k = 0; k < D; ++k) a += xrow[k] * Wa[k*D + d];
        #pragma unroll 8
        for (int k = 0; k < H; ++k) a += hrow[k] * Ua[k*D + d];
    } else {
        #pragma unroll 8
        for (int k = 0; k < H; ++k) a += crow[k] * Ua[(size_t)(H + k)*D + d];
    }
    part[r][p][d] = a;
    __syncthreads();
    if (p == 0) {
        ta[r][d] = tanhf(part[r][0][d] + part[r][1][d]);
    }
    __syncthreads();
    float av = 0.f;
    {
        const int k0 = p * 32;
        #pragma unroll 8
        for (int k = k0; k < k0 + 32; ++k) av += ta[r][k] * Va[k*D + d];
    }
    pv[r][p][d] = av;
    __syncthreads();
    float v = pv[r][0][d] + pv[r][1][d];
    float m = v;
    #pragma unroll
    for (int o = 32; o > 0; o >>= 1) m = fmaxf(m, __shfl_xor(m, o));
    float e = expf(v - m);
    float ssum = e;
    #pragma unroll
    for (int o = 32; o > 0; o >>= 1) ssum += __shfl_xor(ssum, o);
    if (p == 0) {
        float val = (e / ssum) * xrow[d];
        unsigned short hi = f2bf(val);
        unsigned short lo = f2bf(val - bf2f(hi));
        xHi[(size_t)b*D + d] = hi;
        xLo[(size_t)b*D + d] = lo;
    }
}

// Gate GEMM (bf16-split 3-pass MFMA) + fused LSTM update.
// grid (32 ut, 8 rt), 256 thr, waves 2x2 (wr, wc). No per-step conversions:
// A (h/xatt) pre-split planes staged to LDS by copy; B direct swizzled global->reg.
__global__ __launch_bounds__(256) void gates_kernel(
    const unsigned short* __restrict__ wswz,
    const unsigned short* __restrict__ hHi, const unsigned short* __restrict__ hLo,
    const unsigned short* __restrict__ xHi, const unsigned short* __restrict__ xLo,
    float* __restrict__ h32, float* __restrict__ c32,
    const float* __restrict__ bih, const float* __restrict__ bhh, int t)
{
    const int tid = threadIdx.x;
    const int lane = tid & 63;
    const int wid = tid >> 6;
    const int wr = wid >> 1, wc = wid & 1;
    const int ut = blockIdx.x;
    const int rt = blockIdx.y;
    const int b0 = rt * 64;
    const int u_base = ut * 16;
    const int l15 = lane & 15;
    const int cg = lane >> 4;

    __shared__ __align__(16) unsigned short aHi[2][64][72];
    __shared__ __align__(16) unsigned short aLo[2][64][72];
    __shared__ float gout[64][66];

    const int rd = t & 1, wrs = rd ^ 1;
    const unsigned short* __restrict__ hHiR = hHi + (size_t)rd*BH;
    const unsigned short* __restrict__ hLoR = hLo + (size_t)rd*BH;

    f32x4 acc00 = {0,0,0,0}, acc01 = {0,0,0,0}, acc10 = {0,0,0,0}, acc11 = {0,0,0,0};
    short8 bre[2][2][2][2];   // [set][half][ks][rb] — all indices static after unroll

    const int srow = tid >> 2;
    const int q4 = tid & 3;

    auto stageA = [&](int kb, int buf) {
        const unsigned short *sh, *sl;
        if (kb < 8) {
            size_t base = (size_t)(b0 + srow)*H + kb*64 + q4*16;
            sh = hHiR + base; sl = hLoR + base;
        } else {
            size_t base = (size_t)(b0 + srow)*D + q4*16;
            sh = xHi + base; sl = xLo + base;
        }
        *(short8*)&aHi[buf][srow][q4*16]     = *(const short8*)sh;
        *(short8*)&aHi[buf][srow][q4*16 + 8] = *(const short8*)(sh + 8);
        *(short8*)&aLo[buf][srow][q4*16]     = *(const short8*)sl;
        *(short8*)&aLo[buf][srow][q4*16 + 8] = *(const short8*)(sl + 8);
    };
    auto loadB = [&](int kb, int set) {
        #pragma unroll
        for (int half = 0; half < 2; ++half)
            #pragma unroll
            for (int ks = 0; ks < 2; ++ks)
                #pragma unroll
                for (int rb = 0; rb < 2; ++rb) {
                    const unsigned short* p = wswz +
                        ((((size_t)(ut*9 + kb)*2 + half)*2 + ks)*64
                         + wc*32 + rb*16 + l15)*32 + cg*8;
                    bre[set][half][ks][rb] = *(const short8*)p;
                }
    };

    stageA(0, 0);
    loadB(0, 0);
    __syncthreads();

    #pragma unroll
    for (int kb = 0; kb < 9; ++kb) {
        const int cur = kb & 1;
        if (kb < 8) {
            stageA(kb + 1, cur ^ 1);
            loadB(kb + 1, cur ^ 1);
        }
        #pragma unroll
        for (int ks = 0; ks < 2; ++ks) {
            const int col = ks*32 + cg*8;
            short8 ah0 = *(const short8*)&aHi[cur][wr*32 + l15][col];
            short8 ah1 = *(const short8*)&aHi[cur][wr*32 + 16 + l15][col];
            short8 al0 = *(const short8*)&aLo[cur][wr*32 + l15][col];
            short8 al1 = *(const short8*)&aLo[cur][wr*32 + 16 + l15][col];
            short8 bh0 = bre[cur][0][ks][0];
            short8 bh1 = bre[cur][0][ks][1];
            short8 bl0 = bre[cur][1][ks][0];
            short8 bl1 = bre[cur][1][ks][1];
            acc00 = __builtin_amdgcn_mfma_f32_16x16x32_bf16(ah0, bh0, acc00, 0,0,0);
            acc01 = __builtin_amdgcn_mfma_f32_16x16x32_bf16(ah0, bh1, acc01, 0,0,0);
            acc10 = __builtin_amdgcn_mfma_f32_16x16x32_bf16(ah1, bh0, acc10, 0,0,0);
            acc11 = __builtin_amdgcn_mfma_f32_16x16x32_bf16(ah1, bh1, acc11, 0,0,0);
            acc00 = __builtin_amdgcn_mfma_f32_16x16x32_bf16(ah0, bl0, acc00, 0,0,0);
            acc01 = __builtin_amdgcn_mfma_f32_16x16x32_bf16(ah0, bl1, acc01, 0,0,0);
            acc10 = __builtin_amdgcn_mfma_f32_16x16x32_bf16(ah1, bl0, acc10, 0,0,0);
            acc11 = __builtin_amdgcn_mfma_f32_16x16x32_bf16(ah1, bl1, acc11, 0,0,0);
            acc00 = __builtin_amdgcn_mfma_f32_16x16x32_bf16(al0, bh0, acc00, 0,0,0);
            acc01 = __builtin_amdgcn_mfma_f32_16x16x32_bf16(al0, bh1, acc01, 0,0,0);
            acc10 = __builtin_amdgcn_mfma_f32_16x16x32_bf16(al1, bh0, acc10, 0,0,0);
            acc11 = __builtin_amdgcn_mfma_f32_16x16x32_bf16(al1, bh1, acc11, 0,0,0);
        }
        __syncthreads();
    }

    {   // D layout: row=(lane>>4)*4+r, col=lane&15 per 16x16 tile
        const int m0 = (lane >> 4) * 4;
        const int n0 = lane & 15;
        #pragma unroll
        for (int r = 0; r < 4; ++r) {
            gout[wr*32 + m0 + r     ][wc*32 + n0     ] = acc00[r];
            gout[wr*32 + m0 + r     ][wc*32 + 16 + n0] = acc01[r];
            gout[wr*32 + 16 + m0 + r][wc*32 + n0     ] = acc10[r];
            gout[wr*32 + 16 + m0 + r][wc*32 + 16 + n0] = acc11[r];
        }
    }
    __syncthreads();
    {   // fused state update; gates of unit u at cols u16*4 + {0..3}
        const int u16 = tid & 15;
        const int u_glob = u_base + u16;
        const float bs0 = bih[0*H + u_glob] + bhh[0*H + u_glob];
        const float bs1 = bih[1*H + u_glob] + bhh[1*H + u_glob];
        const float bs2 = bih[2*H + u_glob] + bhh[2*H + u_glob];
        const float bs3 = bih[3*H + u_glob] + bhh[3*H + u_glob];
        float* __restrict__ h32w = h32 + (size_t)wrs*BH;
        unsigned short* __restrict__ hHiW = (unsigned short*)hHi + (size_t)wrs*BH;
        unsigned short* __restrict__ hLoW = (unsigned short*)hLo + (size_t)wrs*BH;
        #pragma unroll
        for (int pass = 0; pass < 4; ++pass) {
            const int b_loc = (tid >> 4) + pass*16;
            const int b = b0 + b_loc;
            float2 g01 = *(const float2*)&gout[b_loc][u16*4];
            float2 g23 = *(const float2*)&gout[b_loc][u16*4 + 2];
            float gi = g01.x + bs0;
            float gf = g01.y + bs1;
            float gg = g23.x + bs2;
            float go = g23.y + bs3;
            const size_t idx = (size_t)b*H + u_glob;
            float c_old = c32[idx];
            float si = 1.f/(1.f + expf(-gi));
            float sf = 1.f/(1.f + expf(-gf));
            float so = 1.f/(1.f + expf(-go));
            float cn = sf*c_old + si*tanhf(gg);
            float hn = so*tanhf(cn);
            c32[idx] = cn;
            h32w[idx] = hn;
            unsigned short hi = f2bf(hn);
            unsigned short lo = f2bf(hn - bf2f(hi));
            hHiW[idx] = hi;
            hLoW[idx] = lo;
        }
    }
}

__global__ __launch_bounds__(256) void fc_kernel(
    const float* __restrict__ fcw, const float* __restrict__ fcb,
    const float* __restrict__ h32, float* __restrict__ out)
{
    const int b = blockIdx.x;
    __shared__ float hrow[H];
    const float* __restrict__ hp = h32 + (size_t)b*H;   // final h in slot 0 (S even)
    for (int k = threadIdx.x; k < H; k += 256) hrow[k] = hp[k];
    __syncthreads();
    int j = threadIdx.x;
    if (j < 24) {
        float a = fcb[j];
        #pragma unroll 8
        for (int k = 0; k < H; ++k) a += hrow[k] * fcw[j*H + k];
        out[b*24 + j] = a;
    }
}

extern "C" void kernel_launch(void* const* d_in, const int* in_sizes, int n_in,
                              void* d_out, int out_size, void* d_ws, size_t ws_size,
                              hipStream_t stream) {
    const float* x   = (const float*)d_in[0];
    const float* Wa  = (const float*)d_in[1];
    const float* Ua  = (const float*)d_in[2];
    const float* ba  = (const float*)d_in[3];
    const float* Va  = (const float*)d_in[4];
    const float* Wih = (const float*)d_in[5];
    const float* Whh = (const float*)d_in[6];
    const float* bih = (const float*)d_in[7];
    const float* bhh = (const float*)d_in[8];
    const float* fcw = (const float*)d_in[9];
    const float* fcb = (const float*)d_in[10];
    float* out = (float*)d_out;

    char* base = (char*)d_ws;
    float* h32 = (float*)(base);                                   // 2*BH f32
    float* c32 = (float*)(base + (size_t)2*BH*4);                  // BH f32
    unsigned short* hHi = (unsigned short*)(base + (size_t)3*BH*4);        // 2*BH
    unsigned short* hLo = hHi + (size_t)2*BH;                              // 2*BH
    unsigned short* xHi = hLo + (size_t)2*BH;                              // B*D
    unsigned short* xLo = xHi + (size_t)B*D;                               // B*D
    unsigned short* wswz = xLo + (size_t)B*D;                              // 32*9*2*2*64*32

    hipLaunchKernelGGL(init_zero, dim3((BH + 255)/256), dim3(256), 0, stream,
                       h32, c32, hHi, hLo);
    hipLaunchKernelGGL(prep_weights, dim3(32, 9), dim3(256), 0, stream,
                       Whh, Wih, wswz);
    for (int t = 0; t < S; ++t) {
        hipLaunchKernelGGL(attn_kernel, dim3(B/2), dim3(256), 0, stream,
                           x, Wa, Ua, ba, Va, h32, c32, xHi, xLo, t);
        hipLaunchKernelGGL(gates_kernel, dim3(32, 8), dim3(256), 0, stream,
                           wswz, hHi, hLo, xHi, xLo, h32, c32, bih, bhh, t);
    }
    hipLaunchKernelGGL(fc_kernel, dim3(B), dim3(256), 0, stream, fcw, fcb, h32, out);
}